// Round 2
// baseline (5569.324 us; speedup 1.0000x reference)
//
#include <hip/hip_runtime.h>
#include <cstddef>

#define SS 2048
#define BB 256
#define II 64
#define HH 128

// DPP controls
#define DPP_XOR1 0xB1   // quad_perm [1,0,3,2]  : lane ^= 1
#define DPP_XOR2 0x4E   // quad_perm [2,3,0,1]  : lane ^= 2
#define DPP_HMIR 0x141  // row_half_mirror      : lane k <-> 7-k within 8-lane halves

template<int CTRL>
__device__ __forceinline__ float dpp_add(float v) {
  union { float f; int i; } u, r;
  u.f = v;
  r.i = __builtin_amdgcn_update_dpp(0, u.i, CTRL, 0xF, 0xF, true);
  return v + r.f;
}

// One workgroup per batch element. 512 threads = 8 waves, 1 block/CU.
// slice = tid&7 : 16-wide j-slice of w_hh, 8-wide of w_ih
// idx   = tid>>3: owns hidden indices {idx, idx+64}, each with 3 gate rows.
// __launch_bounds__(512, 2): 2 waves/SIMD target -> 256-VGPR budget so the
// 144 weight floats stay in VGPRs (104-VGPR + AGPR-spill variant wasted
// ~144 accvgpr moves/step; only 1 block/CU is resident anyway).
__global__ __launch_bounds__(512, 2) void gru_fused(
    const float* __restrict__ x,        // [B,S,I]
    const int*   __restrict__ mask,     // [B,S,I]
    const float* __restrict__ x_mean,   // [I]
    const float* __restrict__ w_ih,     // [3H,I]
    const float* __restrict__ w_hh,     // [3H,H]
    const float* __restrict__ b_ih,     // [3H]
    const float* __restrict__ b_hh,     // [3H]
    const float* __restrict__ bn_gamma, // [H]
    const float* __restrict__ bn_beta,  // [H]
    const float* __restrict__ bn_mean,  // [H]
    const float* __restrict__ bn_var,   // [H]
    const float* __restrict__ fc_w,     // [1,H]
    const float* __restrict__ fc_b,     // [1]
    float* __restrict__ out)            // [B,1]
{
  const int b     = blockIdx.x;
  const int tid   = threadIdx.x;
  const int slice = tid & 7;
  const int idx   = tid >> 3;
  const int hx0   = idx;
  const int hx1   = idx + 64;

  // double-buffered: one barrier per step
  __shared__ __align__(16) float xi_lds[2][II];
  __shared__ __align__(16) float h_buf[2][HH];

  // ---- load weights into registers (one time) ----
  float wh[6][16];  // rows: u*3+g, g in {r,z,n}, u in {hx0,hx1}; 16-wide j-slice
  float wi[6][8];   // 8-wide i-slice
  #pragma unroll
  for (int u = 0; u < 2; ++u) {
    const int hh = u ? hx1 : hx0;
    #pragma unroll
    for (int g = 0; g < 3; ++g) {
      const float* pr = w_hh + (size_t)(g * HH + hh) * HH + slice * 16;
      #pragma unroll
      for (int q = 0; q < 4; ++q) {
        float4 v = *reinterpret_cast<const float4*>(pr + q * 4);
        wh[u*3+g][q*4+0] = v.x; wh[u*3+g][q*4+1] = v.y;
        wh[u*3+g][q*4+2] = v.z; wh[u*3+g][q*4+3] = v.w;
      }
      const float* pi = w_ih + (size_t)(g * HH + hh) * II + slice * 8;
      #pragma unroll
      for (int q = 0; q < 2; ++q) {
        float4 v = *reinterpret_cast<const float4*>(pi + q * 4);
        wi[u*3+g][q*4+0] = v.x; wi[u*3+g][q*4+1] = v.y;
        wi[u*3+g][q*4+2] = v.z; wi[u*3+g][q*4+3] = v.w;
      }
    }
  }

  // biases folded into slice 0's accumulator init (reduce gives all lanes the sum)
  float bR[2], bZ[2], bNX[2], bNH[2];
  const bool lead = (slice == 0);
  #pragma unroll
  for (int u = 0; u < 2; ++u) {
    const int hh = u ? hx1 : hx0;
    bR[u]  = lead ? (b_ih[hh]        + b_hh[hh])        : 0.f;
    bZ[u]  = lead ? (b_ih[HH + hh]   + b_hh[HH + hh])   : 0.f;
    bNX[u] = lead ?  b_ih[2*HH + hh]                    : 0.f;
    bNH[u] = lead ?  b_hh[2*HH + hh]                    : 0.f;
  }

  // ---- prologue: LOCF state + first prefetch ----
  const size_t xbase = (size_t)b * SS * II;
  float last = 0.f, xn = 0.f;
  int   mn = 0;
  const float* xq = x + xbase + II + tid;
  const int*   mq = mask + xbase + II + tid;
  if (tid < II) {
    last = x_mean[tid];
    xn   = x[xbase + tid];
    mn   = mask[xbase + tid];
  }
  float hnA = 0.f, hnB = 0.f;  // h[-1] = 0

  for (int t = 0; t < SS; ++t) {
    const int p = t & 1;
    // (a) publish xi[t] and h[t-1] into buffer p
    if (tid < II) {
      last = (mn > 0) ? xn : last;
      xi_lds[p][tid] = last;
    }
    if (slice == 0) { h_buf[p][hx0] = hnA; h_buf[p][hx1] = hnB; }
    __syncthreads();  // single barrier per step (double-buffer covers WAR)

    // (b) prefetch t+1
    if (tid < II && t + 1 < SS) {
      xn = *xq;  mn = *mq;
      xq += II;  mq += II;
    }

    // (c) compute
    const float* hb = h_buf[p];
    const float hp0 = hb[hx0];
    const float hp1 = hb[hx1];

    float xv[8], hv[16];
    #pragma unroll
    for (int q = 0; q < 2; ++q) {
      float4 v = *reinterpret_cast<const float4*>(&xi_lds[p][slice * 8 + q * 4]);
      xv[q*4+0] = v.x; xv[q*4+1] = v.y; xv[q*4+2] = v.z; xv[q*4+3] = v.w;
    }
    // rotated q order: lane addresses spread over banks -> 2-way (free) not 4-way
    #pragma unroll
    for (int qq = 0; qq < 4; ++qq) {
      const int q = (slice + qq) & 3;
      float4 v = *reinterpret_cast<const float4*>(&hb[slice * 16 + q * 4]);
      hv[q*4+0] = v.x; hv[q*4+1] = v.y; hv[q*4+2] = v.z; hv[q*4+3] = v.w;
    }

    float sR[2], sZ[2], sNX[2], sNH[2];
    #pragma unroll
    for (int u = 0; u < 2; ++u) {
      float ar = 0.f, az = 0.f, anh = 0.f;
      float axr = 0.f, axz = 0.f, anx = 0.f;
      #pragma unroll
      for (int j = 0; j < 16; ++j) {
        ar  += wh[u*3+0][j] * hv[j];
        az  += wh[u*3+1][j] * hv[j];
        anh += wh[u*3+2][j] * hv[j];
      }
      #pragma unroll
      for (int i2 = 0; i2 < 8; ++i2) {
        axr += wi[u*3+0][i2] * xv[i2];
        axz += wi[u*3+1][i2] * xv[i2];
        anx += wi[u*3+2][i2] * xv[i2];
      }
      sR[u]  = ar + axr + bR[u];
      sZ[u]  = az + axz + bZ[u];
      sNX[u] = anx + bNX[u];
      sNH[u] = anh + bNH[u];
    }

    // pure-VALU butterfly over the 8 slices (DPP; no LDS/ds_bpermute)
    #pragma unroll
    for (int u = 0; u < 2; ++u) {
      sR[u]  = dpp_add<DPP_XOR1>(sR[u]);
      sZ[u]  = dpp_add<DPP_XOR1>(sZ[u]);
      sNX[u] = dpp_add<DPP_XOR1>(sNX[u]);
      sNH[u] = dpp_add<DPP_XOR1>(sNH[u]);
    }
    #pragma unroll
    for (int u = 0; u < 2; ++u) {
      sR[u]  = dpp_add<DPP_XOR2>(sR[u]);
      sZ[u]  = dpp_add<DPP_XOR2>(sZ[u]);
      sNX[u] = dpp_add<DPP_XOR2>(sNX[u]);
      sNH[u] = dpp_add<DPP_XOR2>(sNH[u]);
    }
    #pragma unroll
    for (int u = 0; u < 2; ++u) {
      sR[u]  = dpp_add<DPP_HMIR>(sR[u]);
      sZ[u]  = dpp_add<DPP_HMIR>(sZ[u]);
      sNX[u] = dpp_add<DPP_HMIR>(sNX[u]);
      sNH[u] = dpp_add<DPP_HMIR>(sNH[u]);
    }

    // gates (all lanes hold full sums after half-mirror stage; slice 0 publishes)
    {
      float r0 = 1.f / (1.f + __expf(-sR[0]));
      float z0 = 1.f / (1.f + __expf(-sZ[0]));
      float a0 = sNX[0] + r0 * sNH[0];
      a0 = fminf(fmaxf(a0, -15.f), 15.f);
      float e0 = __expf(2.f * a0);
      float n0 = (e0 - 1.f) / (e0 + 1.f);
      hnA = (1.f - z0) * n0 + z0 * hp0;

      float r1 = 1.f / (1.f + __expf(-sR[1]));
      float z1 = 1.f / (1.f + __expf(-sZ[1]));
      float a1 = sNX[1] + r1 * sNH[1];
      a1 = fminf(fmaxf(a1, -15.f), 15.f);
      float e1 = __expf(2.f * a1);
      float n1 = (e1 - 1.f) / (e1 + 1.f);
      hnB = (1.f - z1) * n1 + z1 * hp1;
    }
    // no second barrier: next step writes buffer p^1
  }

  // publish final h
  if (slice == 0) { h_buf[0][hx0] = hnA; h_buf[0][hx1] = hnB; }
  __syncthreads();

  // BN (eval) + FC, reduced by wave 0
  if (tid < 64) {
    float p = 0.f;
    #pragma unroll
    for (int q = 0; q < 2; ++q) {
      const int k = tid + q * 64;
      const float hv2 = h_buf[0][k];
      const float nrm = (hv2 - bn_mean[k]) * rsqrtf(bn_var[k] + 1e-5f) * bn_gamma[k] + bn_beta[k];
      p += nrm * fc_w[k];
    }
    #pragma unroll
    for (int off = 32; off > 0; off >>= 1) p += __shfl_down(p, off);
    if (tid == 0) out[b] = p + fc_b[0];
  }
}

extern "C" void kernel_launch(void* const* d_in, const int* in_sizes, int n_in,
                              void* d_out, int out_size, void* d_ws, size_t ws_size,
                              hipStream_t stream) {
  const float* x        = (const float*)d_in[0];
  const int*   mask     = (const int*)  d_in[1];
  // d_in[2] = delta (unused by reference forward)
  const float* x_mean   = (const float*)d_in[3];
  const float* w_ih     = (const float*)d_in[4];
  const float* w_hh     = (const float*)d_in[5];
  const float* b_ih     = (const float*)d_in[6];
  const float* b_hh     = (const float*)d_in[7];
  const float* bn_gamma = (const float*)d_in[8];
  const float* bn_beta  = (const float*)d_in[9];
  const float* bn_mean  = (const float*)d_in[10];
  const float* bn_var   = (const float*)d_in[11];
  const float* fc_w     = (const float*)d_in[12];
  const float* fc_b     = (const float*)d_in[13];
  float* out = (float*)d_out;

  gru_fused<<<dim3(BB), dim3(512), 0, stream>>>(
      x, mask, x_mean, w_ih, w_hh, b_ih, b_hh,
      bn_gamma, bn_beta, bn_mean, bn_var, fc_w, fc_b, out);
}

// Round 3
// 1654.244 us; speedup vs baseline: 3.3667x; 3.3667x over previous
//
#include <hip/hip_runtime.h>
#include <cstddef>

#define SS 2048
#define BB 256
#define II 64
#define HH 128

// DPP controls (all compile-time: no runtime-indexed register arrays anywhere)
#define DPP_XOR1 0xB1   // quad_perm [1,0,3,2]  : lane ^= 1
#define DPP_XOR2 0x4E   // quad_perm [2,3,0,1]  : lane ^= 2
#define DPP_HMIR 0x141  // row_half_mirror      : lane k <-> 7-k within 8-lane halves

template<int CTRL>
__device__ __forceinline__ float dpp_add(float v) {
  union { float f; int i; } u, r;
  u.f = v;
  r.i = __builtin_amdgcn_update_dpp(0, u.i, CTRL, 0xF, 0xF, true);
  return v + r.f;
}

__device__ __forceinline__ float fast_rcp(float v) {
  return __builtin_amdgcn_rcpf(v);  // v_rcp_f32, ~1 ulp: fine vs 2e-2 threshold
}

// One workgroup per batch element; 512 threads = 8 waves; grid 256 = 1 block/CU.
// __launch_bounds__(512, 1): 1 block/CU -> 256-VGPR budget. The (512,2) variant
// capped the allocator at 128 VGPRs (2nd arg = min BLOCKS/CU, CUDA semantics),
// which forced the 144 weight floats to be re-fetched from global EVERY STEP
// (FETCH_SIZE was 132 GB vs 0.27 GB expected).
__global__ __launch_bounds__(512, 1) void gru_fused(
    const float* __restrict__ x,        // [B,S,I]
    const int*   __restrict__ mask,     // [B,S,I]
    const float* __restrict__ x_mean,   // [I]
    const float* __restrict__ w_ih,     // [3H,I]
    const float* __restrict__ w_hh,     // [3H,H]
    const float* __restrict__ b_ih,     // [3H]
    const float* __restrict__ b_hh,     // [3H]
    const float* __restrict__ bn_gamma, // [H]
    const float* __restrict__ bn_beta,  // [H]
    const float* __restrict__ bn_mean,  // [H]
    const float* __restrict__ bn_var,   // [H]
    const float* __restrict__ fc_w,     // [1,H]
    const float* __restrict__ fc_b,     // [1]
    float* __restrict__ out)            // [B,1]
{
  const int b     = blockIdx.x;
  const int tid   = threadIdx.x;
  const int slice = tid & 7;   // K-slice: h[slice*16..+15], xi[slice*8..+7]
  const int idx   = tid >> 3;  // 0..63; owns hidden {idx, idx+64}
  const int hx0   = idx;
  const int hx1   = idx + 64;

  __shared__ __align__(16) float xi_lds[2][II];
  // transposed h store: h[k] lives at word (k&15)*8 + (k>>4).
  // read hv[j] = word j*8+slice -> 8 distinct banks per phase, conflict-free.
  __shared__ float h_tr[2][HH];
  __shared__ float h_fin[HH];

  // ---- weights -> registers (once); all indices static after unroll ----
  float wh[6][16];  // [u*3+g][j], g in {r,z,n}, u in {hx0,hx1}
  float wi[6][8];
  #pragma unroll
  for (int u = 0; u < 2; ++u) {
    const int hh = u ? hx1 : hx0;
    #pragma unroll
    for (int g = 0; g < 3; ++g) {
      const float* pr = w_hh + (size_t)(g * HH + hh) * HH + slice * 16;
      #pragma unroll
      for (int q = 0; q < 4; ++q) {
        float4 v = *reinterpret_cast<const float4*>(pr + q * 4);
        wh[u*3+g][q*4+0] = v.x; wh[u*3+g][q*4+1] = v.y;
        wh[u*3+g][q*4+2] = v.z; wh[u*3+g][q*4+3] = v.w;
      }
      const float* pi = w_ih + (size_t)(g * HH + hh) * II + slice * 8;
      #pragma unroll
      for (int q = 0; q < 2; ++q) {
        float4 v = *reinterpret_cast<const float4*>(pi + q * 4);
        wi[u*3+g][q*4+0] = v.x; wi[u*3+g][q*4+1] = v.y;
        wi[u*3+g][q*4+2] = v.z; wi[u*3+g][q*4+3] = v.w;
      }
    }
  }

  // biases folded into slice 0's partial sums (butterfly gives all lanes the total)
  float bR[2], bZ[2], bNX[2], bNH[2];
  const bool lead = (slice == 0);
  #pragma unroll
  for (int u = 0; u < 2; ++u) {
    const int hh = u ? hx1 : hx0;
    bR[u]  = lead ? (b_ih[hh]      + b_hh[hh])      : 0.f;
    bZ[u]  = lead ? (b_ih[HH+hh]   + b_hh[HH+hh])   : 0.f;
    bNX[u] = lead ?  b_ih[2*HH+hh]                  : 0.f;
    bNH[u] = lead ?  b_hh[2*HH+hh]                  : 0.f;
  }

  // ---- prologue: LOCF state + first prefetch ----
  const size_t xbase = (size_t)b * SS * II;
  float last = 0.f, xn = 0.f;
  int   mn = 0;
  const float* xq = x + xbase + II + tid;
  const int*   mq = mask + xbase + II + tid;
  if (tid < II) {
    last = x_mean[tid];
    xn   = x[xbase + tid];
    mn   = mask[xbase + tid];
  }
  float hcA = 0.f, hcB = 0.f;  // h[t-1][hx0], h[t-1][hx1] carried in-register

  for (int t = 0; t < SS; ++t) {
    const int p = t & 1;
    // publish xi[t] and h[t-1] into buffer p
    if (tid < II) {
      last = (mn > 0) ? xn : last;
      xi_lds[p][tid] = last;
    }
    if (lead) {
      const int tw = (idx & 15) * 8 + (idx >> 4);
      h_tr[p][tw]     = hcA;   // T(idx)
      h_tr[p][tw + 4] = hcB;   // T(idx+64) = T(idx)+4
    }
    __syncthreads();  // one barrier/step; double-buffer covers WAR

    // prefetch t+1 (global, hides under compute)
    if (tid < II && t + 1 < SS) {
      xn = *xq;  mn = *mq;
      xq += II;  mq += II;
    }

    // xi: float4 (2-way bank aliasing = free); h: stride-8-word b32, conflict-free
    float xv[8], hv[16];
    #pragma unroll
    for (int q = 0; q < 2; ++q) {
      float4 v = *reinterpret_cast<const float4*>(&xi_lds[p][slice * 8 + q * 4]);
      xv[q*4+0] = v.x; xv[q*4+1] = v.y; xv[q*4+2] = v.z; xv[q*4+3] = v.w;
    }
    #pragma unroll
    for (int j = 0; j < 16; ++j) hv[j] = h_tr[p][j * 8 + slice];

    float sR[2], sZ[2], sNX[2], sNH[2];
    #pragma unroll
    for (int u = 0; u < 2; ++u) {
      float ar = 0.f, az = 0.f, anh = 0.f;
      float axr = 0.f, axz = 0.f, anx = 0.f;
      #pragma unroll
      for (int j = 0; j < 16; ++j) {
        ar  += wh[u*3+0][j] * hv[j];
        az  += wh[u*3+1][j] * hv[j];
        anh += wh[u*3+2][j] * hv[j];
      }
      #pragma unroll
      for (int i2 = 0; i2 < 8; ++i2) {
        axr += wi[u*3+0][i2] * xv[i2];
        axz += wi[u*3+1][i2] * xv[i2];
        anx += wi[u*3+2][i2] * xv[i2];
      }
      sR[u]  = ar + axr + bR[u];
      sZ[u]  = az + axz + bZ[u];
      sNX[u] = anx + bNX[u];
      sNH[u] = anh + bNH[u];
    }

    // pure-VALU butterfly over 8 slices (no LDS-pipe bpermute)
    #pragma unroll
    for (int u = 0; u < 2; ++u) {
      sR[u]  = dpp_add<DPP_XOR1>(sR[u]);
      sZ[u]  = dpp_add<DPP_XOR1>(sZ[u]);
      sNX[u] = dpp_add<DPP_XOR1>(sNX[u]);
      sNH[u] = dpp_add<DPP_XOR1>(sNH[u]);
    }
    #pragma unroll
    for (int u = 0; u < 2; ++u) {
      sR[u]  = dpp_add<DPP_XOR2>(sR[u]);
      sZ[u]  = dpp_add<DPP_XOR2>(sZ[u]);
      sNX[u] = dpp_add<DPP_XOR2>(sNX[u]);
      sNH[u] = dpp_add<DPP_XOR2>(sNH[u]);
    }
    #pragma unroll
    for (int u = 0; u < 2; ++u) {
      sR[u]  = dpp_add<DPP_HMIR>(sR[u]);
      sZ[u]  = dpp_add<DPP_HMIR>(sZ[u]);
      sNX[u] = dpp_add<DPP_HMIR>(sNX[u]);
      sNH[u] = dpp_add<DPP_HMIR>(sNH[u]);
    }

    // gates: rcp-based sigmoid/tanh (no IEEE div sequences)
    {
      float r0 = fast_rcp(1.f + __expf(-sR[0]));
      float z0 = fast_rcp(1.f + __expf(-sZ[0]));
      float a0 = sNX[0] + r0 * sNH[0];
      a0 = fminf(fmaxf(a0, -15.f), 15.f);
      float n0 = 1.f - 2.f * fast_rcp(__expf(2.f * a0) + 1.f);
      hcA = n0 + z0 * (hcA - n0);

      float r1 = fast_rcp(1.f + __expf(-sR[1]));
      float z1 = fast_rcp(1.f + __expf(-sZ[1]));
      float a1 = sNX[1] + r1 * sNH[1];
      a1 = fminf(fmaxf(a1, -15.f), 15.f);
      float n1 = 1.f - 2.f * fast_rcp(__expf(2.f * a1) + 1.f);
      hcB = n1 + z1 * (hcB - n1);
    }
    // next step writes buffer p^1: no second barrier
  }

  // publish final h
  if (lead) { h_fin[hx0] = hcA; h_fin[hx1] = hcB; }
  __syncthreads();

  // BN (eval) + FC, reduced by wave 0
  if (tid < 64) {
    float pacc = 0.f;
    #pragma unroll
    for (int q = 0; q < 2; ++q) {
      const int k = tid + q * 64;
      const float hv2 = h_fin[k];
      const float nrm = (hv2 - bn_mean[k]) * rsqrtf(bn_var[k] + 1e-5f) * bn_gamma[k] + bn_beta[k];
      pacc += nrm * fc_w[k];
    }
    #pragma unroll
    for (int off = 32; off > 0; off >>= 1) pacc += __shfl_down(pacc, off);
    if (tid == 0) out[b] = pacc + fc_b[0];
  }
}

extern "C" void kernel_launch(void* const* d_in, const int* in_sizes, int n_in,
                              void* d_out, int out_size, void* d_ws, size_t ws_size,
                              hipStream_t stream) {
  const float* x        = (const float*)d_in[0];
  const int*   mask     = (const int*)  d_in[1];
  // d_in[2] = delta (unused by reference forward)
  const float* x_mean   = (const float*)d_in[3];
  const float* w_ih     = (const float*)d_in[4];
  const float* w_hh     = (const float*)d_in[5];
  const float* b_ih     = (const float*)d_in[6];
  const float* b_hh     = (const float*)d_in[7];
  const float* bn_gamma = (const float*)d_in[8];
  const float* bn_beta  = (const float*)d_in[9];
  const float* bn_mean  = (const float*)d_in[10];
  const float* bn_var   = (const float*)d_in[11];
  const float* fc_w     = (const float*)d_in[12];
  const float* fc_b     = (const float*)d_in[13];
  float* out = (float*)d_out;

  gru_fused<<<dim3(BB), dim3(512), 0, stream>>>(
      x, mask, x_mean, w_ih, w_hh, b_ih, b_hh,
      bn_gamma, bn_beta, bn_mean, bn_var, fc_w, fc_b, out);
}

// Round 4
// 1538.569 us; speedup vs baseline: 3.6198x; 1.0752x over previous
//
#include <hip/hip_runtime.h>
#include <cstddef>

#define SS 2048
#define BB 256
#define II 64
#define HH 128

// DPP controls (all compile-time: no runtime-indexed register arrays anywhere)
#define DPP_XOR1 0xB1   // quad_perm [1,0,3,2]  : lane ^= 1
#define DPP_XOR2 0x4E   // quad_perm [2,3,0,1]  : lane ^= 2
#define DPP_HMIR 0x141  // row_half_mirror      : lane k <-> 7-k within 8-lane halves

template<int CTRL>
__device__ __forceinline__ float dpp_add(float v) {
  union { float f; int i; } u, r;
  u.f = v;
  r.i = __builtin_amdgcn_update_dpp(0, u.i, CTRL, 0xF, 0xF, true);
  return v + r.f;
}

__device__ __forceinline__ float fast_rcp(float v) {
  return __builtin_amdgcn_rcpf(v);  // v_rcp_f32, ~1 ulp: fine vs 2e-2 threshold
}

// Opaque identity: the compiler cannot rematerialize an asm output, so the
// value is pinned in a VGPR for its whole live range. Without this, the
// allocator re-loads all 144 loop-invariant weights from cache EVERY timestep
// (R3: VGPR_Count=100 < 144 declared weights, no spill traffic -> remat).
#define KEEP(x) asm volatile("" : "+v"(x))

// One workgroup per batch element; 512 threads = 8 waves; grid 256 = 1 block/CU.
__global__ __launch_bounds__(512, 1) void gru_fused(
    const float* __restrict__ x,        // [B,S,I]
    const int*   __restrict__ mask,     // [B,S,I]
    const float* __restrict__ x_mean,   // [I]
    const float* __restrict__ w_ih,     // [3H,I]
    const float* __restrict__ w_hh,     // [3H,H]
    const float* __restrict__ b_ih,     // [3H]
    const float* __restrict__ b_hh,     // [3H]
    const float* __restrict__ bn_gamma, // [H]
    const float* __restrict__ bn_beta,  // [H]
    const float* __restrict__ bn_mean,  // [H]
    const float* __restrict__ bn_var,   // [H]
    const float* __restrict__ fc_w,     // [1,H]
    const float* __restrict__ fc_b,     // [1]
    float* __restrict__ out)            // [B,1]
{
  const int b     = blockIdx.x;
  const int tid   = threadIdx.x;
  const int slice = tid & 7;   // K-slice: h[slice*16..+15], xi[slice*8..+7]
  const int idx   = tid >> 3;  // 0..63; owns hidden {idx, idx+64}
  const int hx0   = idx;
  const int hx1   = idx + 64;

  __shared__ __align__(16) float xi_lds[2][II];
  // transposed h store: h[k] lives at word (k&15)*8 + (k>>4).
  // read hv[j] = word j*8+slice -> 8 distinct banks per phase, conflict-free.
  __shared__ float h_tr[2][HH];
  __shared__ float h_fin[HH];

  // ---- weights -> registers (once); pinned via KEEP ----
  float wh[6][16];  // [u*3+g][j], g in {r,z,n}, u in {hx0,hx1}
  float wi[6][8];
  #pragma unroll
  for (int u = 0; u < 2; ++u) {
    const int hh = u ? hx1 : hx0;
    #pragma unroll
    for (int g = 0; g < 3; ++g) {
      const float* pr = w_hh + (size_t)(g * HH + hh) * HH + slice * 16;
      #pragma unroll
      for (int q = 0; q < 4; ++q) {
        float4 v = *reinterpret_cast<const float4*>(pr + q * 4);
        wh[u*3+g][q*4+0] = v.x; wh[u*3+g][q*4+1] = v.y;
        wh[u*3+g][q*4+2] = v.z; wh[u*3+g][q*4+3] = v.w;
      }
      const float* pi = w_ih + (size_t)(g * HH + hh) * II + slice * 8;
      #pragma unroll
      for (int q = 0; q < 2; ++q) {
        float4 v = *reinterpret_cast<const float4*>(pi + q * 4);
        wi[u*3+g][q*4+0] = v.x; wi[u*3+g][q*4+1] = v.y;
        wi[u*3+g][q*4+2] = v.z; wi[u*3+g][q*4+3] = v.w;
      }
    }
  }
  #pragma unroll
  for (int r = 0; r < 6; ++r) {
    #pragma unroll
    for (int j = 0; j < 16; ++j) KEEP(wh[r][j]);
    #pragma unroll
    for (int i2 = 0; i2 < 8; ++i2) KEEP(wi[r][i2]);
  }

  // biases folded into slice 0's partial sums (butterfly gives all lanes the total)
  float bR[2], bZ[2], bNX[2], bNH[2];
  const bool lead = (slice == 0);
  #pragma unroll
  for (int u = 0; u < 2; ++u) {
    const int hh = u ? hx1 : hx0;
    bR[u]  = lead ? (b_ih[hh]      + b_hh[hh])      : 0.f;
    bZ[u]  = lead ? (b_ih[HH+hh]   + b_hh[HH+hh])   : 0.f;
    bNX[u] = lead ?  b_ih[2*HH+hh]                  : 0.f;
    bNH[u] = lead ?  b_hh[2*HH+hh]                  : 0.f;
    KEEP(bR[u]); KEEP(bZ[u]); KEEP(bNX[u]); KEEP(bNH[u]);
  }

  // ---- prologue: LOCF state + first prefetch ----
  const size_t xbase = (size_t)b * SS * II;
  float last = 0.f, xn = 0.f;
  int   mn = 0;
  const float* xq = x + xbase + II + tid;
  const int*   mq = mask + xbase + II + tid;
  if (tid < II) {
    last = x_mean[tid];
    xn   = x[xbase + tid];
    mn   = mask[xbase + tid];
  }
  float hcA = 0.f, hcB = 0.f;  // h[t-1][hx0], h[t-1][hx1] carried in-register

  for (int t = 0; t < SS; ++t) {
    const int p = t & 1;
    // publish xi[t] and h[t-1] into buffer p
    if (tid < II) {
      last = (mn > 0) ? xn : last;
      xi_lds[p][tid] = last;
    }
    if (lead) {
      const int tw = (idx & 15) * 8 + (idx >> 4);
      h_tr[p][tw]     = hcA;   // T(idx)
      h_tr[p][tw + 4] = hcB;   // T(idx+64) = T(idx)+4
    }
    __syncthreads();  // one barrier/step; double-buffer covers WAR

    // prefetch t+1 (global, hides under compute)
    if (tid < II && t + 1 < SS) {
      xn = *xq;  mn = *mq;
      xq += II;  mq += II;
    }

    // xi: float4 (2-way bank aliasing = free); h: stride-8-word b32, conflict-free
    float xv[8], hv[16];
    #pragma unroll
    for (int q = 0; q < 2; ++q) {
      float4 v = *reinterpret_cast<const float4*>(&xi_lds[p][slice * 8 + q * 4]);
      xv[q*4+0] = v.x; xv[q*4+1] = v.y; xv[q*4+2] = v.z; xv[q*4+3] = v.w;
    }
    #pragma unroll
    for (int j = 0; j < 16; ++j) hv[j] = h_tr[p][j * 8 + slice];

    float sR[2], sZ[2], sNX[2], sNH[2];
    #pragma unroll
    for (int u = 0; u < 2; ++u) {
      float ar = 0.f, az = 0.f, anh = 0.f;
      float axr = 0.f, axz = 0.f, anx = 0.f;
      #pragma unroll
      for (int j = 0; j < 16; ++j) {
        ar  += wh[u*3+0][j] * hv[j];
        az  += wh[u*3+1][j] * hv[j];
        anh += wh[u*3+2][j] * hv[j];
      }
      #pragma unroll
      for (int i2 = 0; i2 < 8; ++i2) {
        axr += wi[u*3+0][i2] * xv[i2];
        axz += wi[u*3+1][i2] * xv[i2];
        anx += wi[u*3+2][i2] * xv[i2];
      }
      sR[u]  = ar + axr + bR[u];
      sZ[u]  = az + axz + bZ[u];
      sNX[u] = anx + bNX[u];
      sNH[u] = anh + bNH[u];
    }

    // pure-VALU butterfly over 8 slices (no LDS-pipe bpermute)
    #pragma unroll
    for (int u = 0; u < 2; ++u) {
      sR[u]  = dpp_add<DPP_XOR1>(sR[u]);
      sZ[u]  = dpp_add<DPP_XOR1>(sZ[u]);
      sNX[u] = dpp_add<DPP_XOR1>(sNX[u]);
      sNH[u] = dpp_add<DPP_XOR1>(sNH[u]);
    }
    #pragma unroll
    for (int u = 0; u < 2; ++u) {
      sR[u]  = dpp_add<DPP_XOR2>(sR[u]);
      sZ[u]  = dpp_add<DPP_XOR2>(sZ[u]);
      sNX[u] = dpp_add<DPP_XOR2>(sNX[u]);
      sNH[u] = dpp_add<DPP_XOR2>(sNH[u]);
    }
    #pragma unroll
    for (int u = 0; u < 2; ++u) {
      sR[u]  = dpp_add<DPP_HMIR>(sR[u]);
      sZ[u]  = dpp_add<DPP_HMIR>(sZ[u]);
      sNX[u] = dpp_add<DPP_HMIR>(sNX[u]);
      sNH[u] = dpp_add<DPP_HMIR>(sNH[u]);
    }

    // gates: rcp-based sigmoid/tanh (no IEEE div sequences)
    {
      float r0 = fast_rcp(1.f + __expf(-sR[0]));
      float z0 = fast_rcp(1.f + __expf(-sZ[0]));
      float a0 = sNX[0] + r0 * sNH[0];
      a0 = fminf(fmaxf(a0, -15.f), 15.f);
      float n0 = 1.f - 2.f * fast_rcp(__expf(2.f * a0) + 1.f);
      hcA = n0 + z0 * (hcA - n0);

      float r1 = fast_rcp(1.f + __expf(-sR[1]));
      float z1 = fast_rcp(1.f + __expf(-sZ[1]));
      float a1 = sNX[1] + r1 * sNH[1];
      a1 = fminf(fmaxf(a1, -15.f), 15.f);
      float n1 = 1.f - 2.f * fast_rcp(__expf(2.f * a1) + 1.f);
      hcB = n1 + z1 * (hcB - n1);
    }
    // next step writes buffer p^1: no second barrier
  }

  // publish final h
  if (lead) { h_fin[hx0] = hcA; h_fin[hx1] = hcB; }
  __syncthreads();

  // BN (eval) + FC, reduced by wave 0
  if (tid < 64) {
    float pacc = 0.f;
    #pragma unroll
    for (int q = 0; q < 2; ++q) {
      const int k = tid + q * 64;
      const float hv2 = h_fin[k];
      const float nrm = (hv2 - bn_mean[k]) * rsqrtf(bn_var[k] + 1e-5f) * bn_gamma[k] + bn_beta[k];
      pacc += nrm * fc_w[k];
    }
    #pragma unroll
    for (int off = 32; off > 0; off >>= 1) pacc += __shfl_down(pacc, off);
    if (tid == 0) out[b] = pacc + fc_b[0];
  }
}

extern "C" void kernel_launch(void* const* d_in, const int* in_sizes, int n_in,
                              void* d_out, int out_size, void* d_ws, size_t ws_size,
                              hipStream_t stream) {
  const float* x        = (const float*)d_in[0];
  const int*   mask     = (const int*)  d_in[1];
  // d_in[2] = delta (unused by reference forward)
  const float* x_mean   = (const float*)d_in[3];
  const float* w_ih     = (const float*)d_in[4];
  const float* w_hh     = (const float*)d_in[5];
  const float* b_ih     = (const float*)d_in[6];
  const float* b_hh     = (const float*)d_in[7];
  const float* bn_gamma = (const float*)d_in[8];
  const float* bn_beta  = (const float*)d_in[9];
  const float* bn_mean  = (const float*)d_in[10];
  const float* bn_var   = (const float*)d_in[11];
  const float* fc_w     = (const float*)d_in[12];
  const float* fc_b     = (const float*)d_in[13];
  float* out = (float*)d_out;

  gru_fused<<<dim3(BB), dim3(512), 0, stream>>>(
      x, mask, x_mean, w_ih, w_hh, b_ih, b_hh,
      bn_gamma, bn_beta, bn_mean, bn_var, fc_w, fc_b, out);
}